// Round 5
// baseline (19.367 us; speedup 1.0000x reference)
//
#include <hip/hip_runtime.h>
#include <math.h>

// PoolingConnection: out[k,i,j] = max(s[k, 6i:6i+64, 6j:6j+64]) clipped at 384.
// F=128, H=W=384, stride=6, window=64, out=[128,64,64].
//
// H = 64 segments of exactly 6 rows. out[i] = max(segm[i..i+9], segp[i+10])
// (segments >63 -> -inf). segm[g] = 2D-max of rows 6g..6g+5 after W-pooling,
// segp[g] = same over rows 6g..6g+3 only. W-pool per segment: vertical 6-row
// max in registers, then one shuffle sliding-window pass (lane l owns cols
// 6l..6l+5; window j = lanes j..j+9 full + first-4-cols of lane j+10).
//
// ZERO-overlap tiling: K1 block = (k, half), half0 owns segs 0..31, half1 segs
// 32..63 (each input row read exactly once; 32 segs / 16 waves = perfect
// balance). Each block finishes the output rows that are block-local
// (half0: 0..21, half1: 32..63) and exports the 20 boundary segm rows
// (segs 22..41) + 10 segp rows (segs 32..41) to ws; K2 finishes rows 22..31.

constexpr int F  = 128;
constexpr int H  = 384;
constexpr int W  = 384;
constexpr int ST = 6;
constexpr int OH = 64;
constexpr int OW = 64;

#define NINF (-__builtin_huge_valf())

// shuffle value from lane (lane+d); lanes beyond 63 contribute -inf
// (implements the right-edge window clipping for free).
__device__ __forceinline__ float sh_ninf(float v, int lane, int d) {
    float r = __shfl(v, lane + d, 64);
    return (lane + d > 63) ? NINF : r;
}

// sliding max over lanes [l..l+9] of m, plus first-4-cols of lane l+10
__device__ __forceinline__ float slide_window(float m, float p3, int lane) {
    const float a1 = fmaxf(m,  sh_ninf(m,  lane, 1));   // [l, l+1]
    const float a2 = fmaxf(a1, sh_ninf(a1, lane, 2));   // [l .. l+3]
    const float a3 = fmaxf(a2, sh_ninf(a2, lane, 4));   // [l .. l+7]
    const float a4 = fmaxf(a3, sh_ninf(a1, lane, 8));   // [l .. l+9]
    return fmaxf(a4, sh_ninf(p3, lane, 10));            // + 4 cols of l+10
}

// ---------------- K1: main kernel ----------------
__global__ __launch_bounds__(1024) void pool_main(const float* __restrict__ s,
                                                  float* __restrict__ out,
                                                  float* __restrict__ ws_m,
                                                  float* __restrict__ ws_p) {
    __shared__ float segm[42][64];   // 10.5 KiB (rows 32..41 = -inf pad)
    __shared__ float segp[42][64];   // 10.5 KiB

    const int k    = blockIdx.x >> 1;
    const int half = blockIdx.x & 1;
    const int sbeg = half * 32;          // first global segment owned

    const int tid  = threadIdx.x;
    const int wv   = tid >> 6;           // 0..15
    const int lane = tid & 63;

    // -inf pad for local segs 32..41 (bottom clipping; only half1 reads them)
    for (int job = tid; job < 10 * 64; job += 1024) {
        const int g = 32 + (job >> 6);
        const int j = job & 63;
        segm[g][j] = NINF;
        segp[g][j] = NINF;
    }

    // ---- Phase 1: exactly 2 segments per wave (gl = wv, wv+16) ----
    const float* base = s + ((size_t)k * H + sbeg * ST) * W + lane * 6;
    #pragma unroll
    for (int it = 0; it < 2; ++it) {
        const int gl = wv + it * 16;
        const float* seg = base + (size_t)gl * ST * W;
        float vm6 = NINF, vp6 = NINF;    // rows 0..5: all-6-cols / first-4-cols
        float vm4 = NINF, vp4 = NINF;    // rows 0..3 only
        #pragma unroll
        for (int t = 0; t < 6; ++t) {
            const float* row = seg + (size_t)t * W;
            const float2 e0 = *reinterpret_cast<const float2*>(row);
            const float2 e1 = *reinterpret_cast<const float2*>(row + 2);
            const float2 e2 = *reinterpret_cast<const float2*>(row + 4);
            const float p3 = fmaxf(fmaxf(e0.x, e0.y), fmaxf(e1.x, e1.y));
            const float m  = fmaxf(p3, fmaxf(e2.x, e2.y));
            vm6 = fmaxf(vm6, m);
            vp6 = fmaxf(vp6, p3);
            if (t < 4) { vm4 = fmaxf(vm4, m); vp4 = fmaxf(vp4, p3); }
        }
        segm[gl][lane] = slide_window(vm6, vp6, lane);
        segp[gl][lane] = slide_window(vm4, vp4, lane);
    }
    __syncthreads();

    // ---- Export boundary segments to workspace ----
    // ws_m[k][g] = segm_global[22+g], g=0..19 ; ws_p[k][g] = segp_global[32+g], g=0..9
    if (!half) {
        for (int job = tid; job < 10 * 64; job += 1024) {
            const int g = job >> 6, c = job & 63;
            ws_m[((size_t)k * 20 + g) * 64 + c] = segm[22 + g][c];   // segs 22..31
        }
    } else {
        for (int job = tid; job < 20 * 64; job += 1024) {
            const int g = job >> 6, c = job & 63;
            if (g < 10) ws_m[((size_t)k * 20 + 10 + g) * 64 + c] = segm[g][c];  // 32..41
            else        ws_p[((size_t)k * 10 + (g - 10)) * 64 + c] = segp[g - 10][c];
        }
    }

    // ---- Phase 2: block-local output rows ----
    // half0: rows 0..21 (local seg idx == li); half1: rows 32..63 (local == li)
    const int obeg = half ? 32 : 0;
    const int ni   = half ? 32 : 22;
    for (int job = tid; job < ni * 64; job += 1024) {
        const int li = job >> 6;
        const int j  = job & 63;
        float acc = segp[li + 10][j];
        #pragma unroll
        for (int t = 0; t < 10; ++t) acc = fmaxf(acc, segm[li + t][j]);
        out[((size_t)k * OH + obeg + li) * OW + j] = acc;   // coalesced
    }
}

// ---------------- K2: boundary rows 22..31 ----------------
// One wave per (k, r): out[k][22+r][j] = max(ws_m[k][r..r+9][j], ws_p[k][r][j])
__global__ __launch_bounds__(256) void pool_fixup(const float* __restrict__ ws_m,
                                                  const float* __restrict__ ws_p,
                                                  float* __restrict__ out) {
    const int gtid = blockIdx.x * 256 + threadIdx.x;
    const int wid  = gtid >> 6;
    const int lane = gtid & 63;
    if (wid >= F * 10) return;
    const int k = wid / 10;
    const int r = wid % 10;

    const float* m = ws_m + ((size_t)k * 20 + r) * 64 + lane;
    float acc = ws_p[((size_t)k * 10 + r) * 64 + lane];     // segp_global[32+r]
    #pragma unroll
    for (int t = 0; t < 10; ++t) acc = fmaxf(acc, m[(size_t)t * 64]);
    out[((size_t)k * OH + 22 + r) * OW + lane] = acc;       // coalesced
}

extern "C" void kernel_launch(void* const* d_in, const int* in_sizes, int n_in,
                              void* d_out, int out_size, void* d_ws, size_t ws_size,
                              hipStream_t stream) {
    const float* s = (const float*)d_in[0];
    float* out     = (float*)d_out;
    float* ws_m    = (float*)d_ws;                 // [128][20][64] floats
    float* ws_p    = ws_m + (size_t)F * 20 * 64;   // [128][10][64] floats

    pool_main<<<F * 2, 1024, 0, stream>>>(s, out, ws_m, ws_p);
    pool_fixup<<<(F * 10 * 64 + 255) / 256, 256, 0, stream>>>(ws_m, ws_p, out);
}

// Round 7
// 19.199 us; speedup vs baseline: 1.0088x; 1.0088x over previous
//
#include <hip/hip_runtime.h>
#include <math.h>

// PoolingConnection fused: out[k,i,j] = max(s[k, 6i:6i+64, 6j:6j+64]) clipped at 384.
// F=128, H=W=384, stride=6, window=64, out=[128,64,64].
//
// H = 64 segments of exactly 6 rows. out[i] = max(segm[i..i+9], segp[i+10])
// (segments > 63 -> -inf). segm[g] = 2D max of rows 6g..6g+5 (W-pooled),
// segp[g] = rows 6g..6g+3 only.
//
// Phase 1 per segment (one wave): the 6-row segment is 9216 CONTIGUOUS bytes
// = 9 perfectly-coalesced float4 loads (1024B/instr). Element (i,l,j) has
// col (256i+4l+j) mod 384; 256i mod 384 has period 3, so per-lane class maxes
//   P0=max(L0,L3) P1=max(L1,L4) P2=max(L2,L5)      (rows 0..3 = loads 0..5)
//   V0=max(P0,L6) V1=max(P1,L7) V2=max(P2,L8)      (rows 0..5)
// give every column exactly two holders. Both land in LDS arrays laid out as
// "float4 q <-> cols 4q..4q+3":
//   A[l]=V0 ; l<32: A[64+l]=V1 else B[l-32]=V1 ; B[32+l]=V2   (each col once
//   in A, once in B). colmax[c] = max(A[c], B[c]).
// Regroup read: lane g reads float2 pairs 3g,3g+1,3g+2 (cols 6g..6g+5), then
// the proven shuffle sliding-window. wave_barrier() fences compiler reordering
// of the intra-wave LDS exchange (round-6 bug); HW LDS is in-order per wave.
//
// Tiling = round 4: block=(k,half); half0 segs 0..36 / out rows 0..26,
// half1 segs 27..63 / out rows 27..63.

constexpr int F  = 128;
constexpr int H  = 384;
constexpr int W  = 384;
constexpr int ST = 6;
constexpr int OH = 64;
constexpr int OW = 64;

constexpr int NSEG   = 37;        // segments per half
constexpr int SEGPAD = NSEG + 10; // -inf padded for fixed 10-tap combine

#define NINF (-__builtin_huge_valf())

__device__ __forceinline__ float sh_ninf(float v, int lane, int d) {
    float r = __shfl(v, lane + d, 64);
    return (lane + d > 63) ? NINF : r;
}

// sliding max over lanes [l..l+9] of m, plus first-4-cols of lane l+10
__device__ __forceinline__ float slide_window(float m, float p3, int lane) {
    const float a1 = fmaxf(m,  sh_ninf(m,  lane, 1));   // [l, l+1]
    const float a2 = fmaxf(a1, sh_ninf(a1, lane, 2));   // [l .. l+3]
    const float a3 = fmaxf(a2, sh_ninf(a2, lane, 4));   // [l .. l+7]
    const float a4 = fmaxf(a3, sh_ninf(a1, lane, 8));   // [l .. l+9]
    return fmaxf(a4, sh_ninf(p3, lane, 10));            // + 4 cols of l+10
}

__device__ __forceinline__ float4 fmax4(float4 a, float4 b) {
    float4 r;
    r.x = fmaxf(a.x, b.x); r.y = fmaxf(a.y, b.y);
    r.z = fmaxf(a.z, b.z); r.w = fmaxf(a.w, b.w);
    return r;
}

__device__ __forceinline__ float2 fmax2f(float2 a, float2 b) {
    float2 r; r.x = fmaxf(a.x, b.x); r.y = fmaxf(a.y, b.y); return r;
}

__global__ __launch_bounds__(1024) void pool_fused_kernel(const float* __restrict__ s,
                                                          float* __restrict__ out) {
    __shared__ float  segm[SEGPAD][64];   // 11.75 KiB
    __shared__ float  segp[SEGPAD][64];   // 11.75 KiB
    __shared__ float4 cmA[16][96];        // 24 KiB  (6-row classes)
    __shared__ float4 cmB[16][96];        // 24 KiB
    __shared__ float4 ppA[16][96];        // 24 KiB  (4-row classes)
    __shared__ float4 ppB[16][96];        // 24 KiB

    const int k    = blockIdx.x >> 1;
    const int half = blockIdx.x & 1;
    const int sbeg = half ? 27 : 0;   // first global segment this block computes
    const int obeg = half ? 27 : 0;   // first output row
    const int ni   = half ? 37 : 27;  // output rows produced

    const int tid  = threadIdx.x;
    const int wv   = tid >> 6;        // 0..15
    const int lane = tid & 63;

    // -inf pad for local segs 37..46 (bottom clipping for out i >= 54)
    for (int job = tid; job < 10 * 64; job += 1024) {
        const int g = NSEG + (job >> 6);
        const int j = job & 63;
        segm[g][j] = NINF;
        segp[g][j] = NINF;
    }

    float4* wA = cmA[wv];
    float4* wB = cmB[wv];
    float4* qA = ppA[wv];
    float4* qB = ppB[wv];

    // ---- Phase 1: segments gl = wv, wv+16, (wv+32 if < 37) ----
    const float* base = s + ((size_t)k * H + sbeg * ST) * W;
    for (int gl = wv; gl < NSEG; gl += 16) {
        const float* sp = base + (size_t)gl * ST * W + 4 * lane;

        // 9 perfectly-coalesced float4 loads (whole 6-row segment, flat)
        const float4 L0 = *reinterpret_cast<const float4*>(sp);
        const float4 L1 = *reinterpret_cast<const float4*>(sp + 256);
        const float4 L2 = *reinterpret_cast<const float4*>(sp + 512);
        const float4 L3 = *reinterpret_cast<const float4*>(sp + 768);
        const float4 L4 = *reinterpret_cast<const float4*>(sp + 1024);
        const float4 L5 = *reinterpret_cast<const float4*>(sp + 1280);
        const float4 L6 = *reinterpret_cast<const float4*>(sp + 1536);
        const float4 L7 = *reinterpret_cast<const float4*>(sp + 1792);
        const float4 L8 = *reinterpret_cast<const float4*>(sp + 2048);

        const float4 P0 = fmax4(L0, L3), P1 = fmax4(L1, L4), P2 = fmax4(L2, L5);
        const float4 V0 = fmax4(P0, L6), V1 = fmax4(P1, L7), V2 = fmax4(P2, L8);

        __builtin_amdgcn_wave_barrier();   // fence vs previous iteration's reads

        // scatter class vectors: both A and B end up "float4 q <-> cols 4q..4q+3"
        wA[lane] = V0;  qA[lane] = P0;
        if (lane < 32) { wA[64 + lane] = V1;  qA[64 + lane] = P1; }
        else           { wB[lane - 32] = V1;  qB[lane - 32] = P1; }
        wB[32 + lane] = V2;  qB[32 + lane] = P2;

        __builtin_amdgcn_wave_barrier();   // writes complete (in-order LDS) before reads

        // regroup read: lane g -> cols 6g..6g+5 (float2 pairs 3g..3g+2)
        const float2* rA = reinterpret_cast<const float2*>(wA);
        const float2* rB = reinterpret_cast<const float2*>(wB);
        const float2 c0 = fmax2f(rA[3 * lane],     rB[3 * lane]);
        const float2 c1 = fmax2f(rA[3 * lane + 1], rB[3 * lane + 1]);
        const float2 c2 = fmax2f(rA[3 * lane + 2], rB[3 * lane + 2]);

        const float2* sA = reinterpret_cast<const float2*>(qA);
        const float2* sB = reinterpret_cast<const float2*>(qB);
        const float2 d0 = fmax2f(sA[3 * lane],     sB[3 * lane]);
        const float2 d1 = fmax2f(sA[3 * lane + 1], sB[3 * lane + 1]);
        const float2 d2 = fmax2f(sA[3 * lane + 2], sB[3 * lane + 2]);

        __builtin_amdgcn_wave_barrier();   // reads done before next iter's writes

        const float p3c = fmaxf(fmaxf(c0.x, c0.y), fmaxf(c1.x, c1.y)); // first 4 cols
        const float mc  = fmaxf(p3c, fmaxf(c2.x, c2.y));               // all 6 cols
        segm[gl][lane] = slide_window(mc, p3c, lane);

        const float p3p = fmaxf(fmaxf(d0.x, d0.y), fmaxf(d1.x, d1.y));
        const float mp  = fmaxf(p3p, fmaxf(d2.x, d2.y));
        segp[gl][lane] = slide_window(mp, p3p, lane);
    }
    __syncthreads();

    // ---- Phase 2: out[obeg+li] = max(segm[li..li+9], segp[li+10]) ----
    for (int job = tid; job < ni * 64; job += 1024) {
        const int li = job >> 6;
        const int j  = job & 63;
        float acc = segp[li + 10][j];
        #pragma unroll
        for (int t = 0; t < 10; ++t) acc = fmaxf(acc, segm[li + t][j]);
        out[((size_t)k * OH + obeg + li) * OW + j] = acc;   // coalesced
    }
}

extern "C" void kernel_launch(void* const* d_in, const int* in_sizes, int n_in,
                              void* d_out, int out_size, void* d_ws, size_t ws_size,
                              hipStream_t stream) {
    const float* s = (const float*)d_in[0];
    float* out     = (float*)d_out;
    pool_fused_kernel<<<F * 2, 1024, 0, stream>>>(s, out);
}